// Round 11
// baseline (414.009 us; speedup 1.0000x reference)
//
#include <hip/hip_runtime.h>
#include <hip/hip_bf16.h>
#include <stdint.h>

#define NT   204800      // nodes
#define NE   3276800     // edges
#define ED   64          // embed dim
#define NBG  8192        // graphs
#define HID  1600        // 25*64
#define HPAD 1664        // 13*128
#define CAP  56          // per-node list capacity (Poisson(16) max indegree ~38)
#define NBKT 400         // dst>>9 -> 400 buckets of 512 nodes
#define BCAP 9216        // per-bucket record capacity (mean 8192, +11 sigma)
#define NTL  50          // src tiles (src>>12) for the in-bucket locality sort

typedef float  f32x4  __attribute__((ext_vector_type(4)));
typedef __bf16 bf16x8 __attribute__((ext_vector_type(8)));

__device__ __forceinline__ void async_ld16(const void* g, void* l) {
    __builtin_amdgcn_global_load_lds(
        (__attribute__((address_space(1))) const void*)g,
        (__attribute__((address_space(3))) void*)l, 16, 0, 0);
}

// bf16 bits of a float (round-to-nearest-even via intrinsic, reinterpret raw)
__device__ __forceinline__ unsigned short f2bf_raw(float f) {
    __hip_bfloat16 h = __float2bfloat16(f);
    return *(unsigned short*)&h;
}

// ---------- init: bucket cursors + logit accumulators ----------
__global__ void k_init(int* __restrict__ gcur, float* __restrict__ logits) {
    int i = blockIdx.x * 256 + threadIdx.x;   // 64 blocks x 256 = 16384
    if (i < NBKT) gcur[i] = i * BCAP;
    logits[i] = 0.f;                          // 2*NBG = 16384
}

// ---------- pass A: radix-partition edges into 400 dst-range buckets ----------
// packed record = (src<<9) | (dst & 511); 512 blocks -> 2 waves/SIMD occupancy
__global__ __launch_bounds__(256) void k_part(const int* __restrict__ srcv,
                                              const int* __restrict__ dstv,
                                              int* __restrict__ gcur,
                                              unsigned* __restrict__ rec) {
    __shared__ int hist[NBKT];
    __shared__ int slot[NBKT];
    __shared__ int gofs[NBKT];
    const int t = threadIdx.x;
    const int base = blockIdx.x * (NE / 512);   // 6400-edge chunk
    for (int i = t; i < NBKT; i += 256) { hist[i] = 0; slot[i] = 0; }
    __syncthreads();
    for (int j = 0; j < 25; ++j) {
        int d = dstv[base + j * 256 + t];
        atomicAdd(&hist[d >> 9], 1);
    }
    __syncthreads();
    for (int i = t; i < NBKT; i += 256) gofs[i] = atomicAdd(&gcur[i], hist[i]);
    __syncthreads();
    for (int j = 0; j < 25; ++j) {
        int i = base + j * 256 + t;
        int d = dstv[i];
        int s = srcv[i];
        int b = d >> 9;
        int ls = atomicAdd(&slot[b], 1);
        int idx = gofs[b] + ls;
        if (idx < (b + 1) * BCAP)   // overflow guard (P ~ 0)
            rec[idx] = ((unsigned)s << 9) | (unsigned)(d & 511);
    }
}

// ---------- pass B: src-tile counting sort (locality) + CSR fill + dinv ----------
// Records sorted by src>>12 before slot assignment -> per-node lists hold srcs
// in ~ascending order -> concurrent gather waves walk a moving src band.
__global__ __launch_bounds__(512) void k_fillb(const int* __restrict__ gcur,
                                               const unsigned* __restrict__ rec,
                                               int* __restrict__ cur,
                                               int* __restrict__ csr,
                                               float* __restrict__ dinv) {
    __shared__ unsigned rs[BCAP];   // 36.9 KB tile-sorted records
    __shared__ int hist[NTL];
    __shared__ int ofs[NTL];
    __shared__ int cnt[512];
    const int t = threadIdx.x;
    const int b = blockIdx.x;
    const int n0 = b * 512;
    if (t < NTL) hist[t] = 0;
    cnt[t] = 0;
    __syncthreads();
    const unsigned* gr = rec + (size_t)b * BCAP;
    int bcnt = gcur[b] - b * BCAP;
    bcnt = (bcnt > BCAP) ? BCAP : bcnt;
    // pass 1: tile histogram (src>>12 == r>>21)
    for (int i = t; i < bcnt; i += 512) atomicAdd(&hist[gr[i] >> 21], 1);
    __syncthreads();
    if (t == 0) {
        int a = 0;
        for (int i = 0; i < NTL; ++i) { ofs[i] = a; a += hist[i]; }
    }
    __syncthreads();
    // pass 2: scatter into tile-sorted LDS order
    for (int i = t; i < bcnt; i += 512) {
        unsigned r = gr[i];
        int p = atomicAdd(&ofs[r >> 21], 1);
        rs[p] = r;
    }
    __syncthreads();
    // pass 3: fill csr sweeping sorted records (slot order ~ ascending src tile)
    for (int i = t; i < bcnt; i += 512) {
        unsigned r = rs[i];
        unsigned rel = r & 511u;
        int ls = atomicAdd(&cnt[rel], 1);
        if (ls < CAP) csr[(size_t)(n0 + rel) * CAP + ls] = (int)(r >> 9);
    }
    __syncthreads();
    int cn = cnt[t];
    cur[n0 + t] = cn;
    dinv[n0 + t] = rsqrtf((float)cn + 1.f);   // +1 self-loop
}

// ---------- hbs = bf16( (x @ W_conv) * dinv[row] )  (bf16 MFMA, 64x64x64 tile) ----------
__global__ __launch_bounds__(256) void k_gemm_conv(const float* __restrict__ x,
                                                   const float* __restrict__ Wc,
                                                   const float* __restrict__ dinv,
                                                   __hip_bfloat16* __restrict__ hbs) {
    __shared__ unsigned short Xs[64 * 72];   // [row][k] bf16, padded
    __shared__ unsigned short Wt[64 * 72];   // [n][k] bf16 (Wc transposed), padded
    const int t = threadIdx.x;
    const int row0 = blockIdx.x * 64;
#pragma unroll
    for (int i = 0; i < 4; ++i) {
        int idx = i * 256 + t;                 // f32x4 units, 0..1023
        int r = idx >> 4, c4 = (idx & 15) << 2;
        f32x4 wv = ((const f32x4*)Wc)[idx];    // Wc[r][c4..c4+3]
        Wt[(c4 + 0) * 72 + r] = f2bf_raw(wv.x);
        Wt[(c4 + 1) * 72 + r] = f2bf_raw(wv.y);
        Wt[(c4 + 2) * 72 + r] = f2bf_raw(wv.z);
        Wt[(c4 + 3) * 72 + r] = f2bf_raw(wv.w);
        f32x4 xv = ((const f32x4*)(x + (size_t)row0 * 64))[idx];
        ushort4 p;
        p.x = f2bf_raw(xv.x);
        p.y = f2bf_raw(xv.y);
        p.z = f2bf_raw(xv.z);
        p.w = f2bf_raw(xv.w);
        *(ushort4*)&Xs[r * 72 + c4] = p;
    }
    __syncthreads();
    const int w = t >> 6, lane = t & 63;
    const int fr = lane & 15, fq = lane >> 4;
    f32x4 acc[4] = {};
#pragma unroll
    for (int kb = 0; kb < 2; ++kb) {
        bf16x8 av = *(const bf16x8*)&Xs[(w * 16 + fr) * 72 + kb * 32 + fq * 8];
#pragma unroll
        for (int j = 0; j < 4; ++j) {
            bf16x8 bv = *(const bf16x8*)&Wt[(j * 16 + fr) * 72 + kb * 32 + fq * 8];
            acc[j] = __builtin_amdgcn_mfma_f32_16x16x32_bf16(av, bv, acc[j], 0, 0, 0);
        }
    }
#pragma unroll
    for (int r = 0; r < 4; ++r) {
        int row = row0 + w * 16 + fq * 4 + r;
        float di = dinv[row];
        unsigned short* dst = (unsigned short*)&hbs[(size_t)row * 64];
#pragma unroll
        for (int j = 0; j < 4; ++j)
            dst[j * 16 + fr] = f2bf_raw(acc[j][r] * di);
    }
}

// ---------- gather: one wave per node, lane = channel, 8 rows in flight ----------
// Hb[d] = bf16( relu( bc + dinv[d] * ( hbs[d] + sum_src hbs[src] ) ) )
__global__ __launch_bounds__(256) void k_gather(const int* __restrict__ cur,
                                                const int* __restrict__ csr,
                                                const float* __restrict__ dinv,
                                                const __hip_bfloat16* __restrict__ hbs,
                                                const float* __restrict__ bc,
                                                __hip_bfloat16* __restrict__ Hb) {
    const int lane = threadIdx.x & 63;
    const int d = blockIdx.x * 4 + (threadIdx.x >> 6);
    const float di = dinv[d];
    int cn = cur[d];
    cn = (cn > CAP) ? CAP : cn;
    int me = (lane < cn) ? __builtin_nontemporal_load(&csr[(size_t)d * CAP + lane]) : 0;
    float acc = __bfloat162float(hbs[(size_t)d * ED + lane]);   // self-loop term
    int e = 0;
    for (; e + 8 <= cn; e += 8) {
        int s0 = __shfl(me, e,     64);
        int s1 = __shfl(me, e + 1, 64);
        int s2 = __shfl(me, e + 2, 64);
        int s3 = __shfl(me, e + 3, 64);
        int s4 = __shfl(me, e + 4, 64);
        int s5 = __shfl(me, e + 5, 64);
        int s6 = __shfl(me, e + 6, 64);
        int s7 = __shfl(me, e + 7, 64);
        float h0 = __bfloat162float(hbs[(size_t)s0 * ED + lane]);
        float h1 = __bfloat162float(hbs[(size_t)s1 * ED + lane]);
        float h2 = __bfloat162float(hbs[(size_t)s2 * ED + lane]);
        float h3 = __bfloat162float(hbs[(size_t)s3 * ED + lane]);
        float h4 = __bfloat162float(hbs[(size_t)s4 * ED + lane]);
        float h5 = __bfloat162float(hbs[(size_t)s5 * ED + lane]);
        float h6 = __bfloat162float(hbs[(size_t)s6 * ED + lane]);
        float h7 = __bfloat162float(hbs[(size_t)s7 * ED + lane]);
        acc += ((h0 + h1) + (h2 + h3)) + ((h4 + h5) + (h6 + h7));
    }
    for (; e < cn; ++e) {
        int s = __shfl(me, e, 64);
        acc += __bfloat162float(hbs[(size_t)s * ED + lane]);
    }
    Hb[(size_t)d * ED + lane] = __float2bfloat16(fmaxf(bc[lane] + di * acc, 0.f));
}

// ---------- W1 -> bf16, transposed [HPAD][HID] ----------
__global__ void k_convW1(const float* __restrict__ W1, __hip_bfloat16* __restrict__ Bt) {
    __shared__ float tile[64][65];
    const int t = threadIdx.x;
    const int k0 = blockIdx.x * 64;   // 25 tiles
    const int n0 = blockIdx.y * 64;   // 26 tiles (pad zero)
#pragma unroll
    for (int i = 0; i < 16; ++i) {
        int lin = i * 256 + t;
        int r = lin >> 6, c = lin & 63;
        int n = n0 + c;
        tile[r][c] = (n < HID) ? W1[(size_t)(k0 + r) * HID + n] : 0.f;
    }
    __syncthreads();
#pragma unroll
    for (int i = 0; i < 16; ++i) {
        int lin = i * 256 + t;
        int nn = lin >> 6, kk = lin & 63;
        Bt[(size_t)(n0 + nn) * HID + k0 + kk] = __float2bfloat16(tile[kk][nn]);
    }
}

// ---------- fused: logits += relu(Hb @ W1 + b1) @ W2  (bf16 MFMA + epilogue reduce) ----------
__global__ __launch_bounds__(256) void k_gemm1(const __hip_bfloat16* __restrict__ A,
                                               const __hip_bfloat16* __restrict__ Bt,
                                               const float* __restrict__ b1,
                                               const float* __restrict__ W2,
                                               float* __restrict__ logits) {
    __shared__ unsigned short As[128 * 32];
    __shared__ unsigned short Bs[128 * 32];
    const int t = threadIdx.x;
    const int lane = t & 63;
    const int wave = t >> 6;
    const int bm0 = blockIdx.x * 128;
    const int bn0 = blockIdx.y * 128;
    const int wm = (wave >> 1) * 64;
    const int wn = (wave & 1) * 64;
    const int fr = lane & 15;
    const int fq = lane >> 4;
    const int sr = t >> 2;
    const int sc = (t & 3) * 8;
    const __hip_bfloat16* ga0 = A + (size_t)(bm0 + sr) * HID + sc;
    const __hip_bfloat16* ga1 = A + (size_t)(bm0 + 64 + sr) * HID + sc;
    const __hip_bfloat16* gb0 = Bt + (size_t)(bn0 + sr) * HID + sc;
    const __hip_bfloat16* gb1 = Bt + (size_t)(bn0 + 64 + sr) * HID + sc;
    unsigned short* lA0 = &As[t * 8];
    unsigned short* lA1 = &As[(256 + t) * 8];
    unsigned short* lB0 = &Bs[t * 8];
    unsigned short* lB1 = &Bs[(256 + t) * 8];
    const unsigned short* fa0 = &As[(wm + fr) * 32 + fq * 8];
    const unsigned short* fb0 = &Bs[(wn + fr) * 32 + fq * 8];
    f32x4 acc[4][4] = {};
    for (int k0 = 0; k0 < HID; k0 += 32) {
        async_ld16(ga0, lA0); async_ld16(ga1, lA1);
        async_ld16(gb0, lB0); async_ld16(gb1, lB1);
        ga0 += 32; ga1 += 32; gb0 += 32; gb1 += 32;
        __syncthreads();
        bf16x8 av[4], bv[4];
#pragma unroll
        for (int i = 0; i < 4; ++i) av[i] = *(const bf16x8*)(fa0 + i * 16 * 32);
#pragma unroll
        for (int j = 0; j < 4; ++j) bv[j] = *(const bf16x8*)(fb0 + j * 16 * 32);
#pragma unroll
        for (int i = 0; i < 4; ++i)
#pragma unroll
            for (int j = 0; j < 4; ++j)
                acc[i][j] = __builtin_amdgcn_mfma_f32_16x16x32_bf16(av[i], bv[j], acc[i][j], 0, 0, 0);
        __syncthreads();
    }
    // epilogue: fold relu(h2)·W2 into per-row logit partials; h2 never hits memory
    float biasj[4], w2x[4], w2y[4];
#pragma unroll
    for (int j = 0; j < 4; ++j) {
        int n = bn0 + wn + j * 16 + fr;
        if (n < HID) {
            biasj[j] = b1[n];
            float2 w = ((const float2*)W2)[n];
            w2x[j] = w.x; w2y[j] = w.y;
        } else { biasj[j] = 0.f; w2x[j] = 0.f; w2y[j] = 0.f; }
    }
#pragma unroll
    for (int i = 0; i < 4; ++i) {
#pragma unroll
        for (int r = 0; r < 4; ++r) {
            float a0 = 0.f, a1 = 0.f;
#pragma unroll
            for (int j = 0; j < 4; ++j) {
                float v = fmaxf(acc[i][j][r] + biasj[j], 0.f);
                a0 += v * w2x[j];
                a1 += v * w2y[j];
            }
            // reduce across the 16 fr-lanes (low 4 lane bits)
            a0 += __shfl_xor(a0, 1, 64); a1 += __shfl_xor(a1, 1, 64);
            a0 += __shfl_xor(a0, 2, 64); a1 += __shfl_xor(a1, 2, 64);
            a0 += __shfl_xor(a0, 4, 64); a1 += __shfl_xor(a1, 4, 64);
            a0 += __shfl_xor(a0, 8, 64); a1 += __shfl_xor(a1, 8, 64);
            if (fr == 0) {
                int m = bm0 + wm + i * 16 + fq * 4 + r;
                unsafeAtomicAdd(&logits[2 * m],     a0);
                unsafeAtomicAdd(&logits[2 * m + 1], a1);
            }
        }
    }
}

// ---------- softmax over accumulated logits ----------
__global__ void k_soft(const float* __restrict__ logits, const float* __restrict__ b2,
                       float* __restrict__ out) {
    int g = blockIdx.x * 256 + threadIdx.x;
    float l0 = logits[2 * g]     + b2[0];
    float l1 = logits[2 * g + 1] + b2[1];
    float mx = fmaxf(l0, l1);
    float e0 = expf(l0 - mx), e1 = expf(l1 - mx);
    float s = e0 + e1;
    out[2 * g]     = e0 / s;
    out[2 * g + 1] = e1 / s;
}

extern "C" void kernel_launch(void* const* d_in, const int* in_sizes, int n_in,
                              void* d_out, int out_size, void* d_ws, size_t ws_size,
                              hipStream_t stream) {
    const float* x  = (const float*)d_in[0];
    const int*   ei = (const int*)d_in[1];
    // d_in[2] = batch (unused; reshape handles grouping)
    const float* Wc = (const float*)d_in[3];
    const float* bc = (const float*)d_in[4];
    const float* W1 = (const float*)d_in[5];
    const float* b1 = (const float*)d_in[6];
    const float* W2 = (const float*)d_in[7];
    const float* b2 = (const float*)d_in[8];
    float* out = (float*)d_out;

    const int* srcv = ei;
    const int* dstv = ei + NE;

    // workspace layout (bytes):
    //   cur    : [0,         819200)
    //   dinv   : [819200,    1638400)
    //   gcur   : [1638400,   1640000)
    //   csr    : [1642496,   47517696)    int[NT*CAP]
    //   rec    : [47517696,  62263296)    unsigned[NBKT*BCAP]; dead after k_fillb
    //     hbs  : [47517696,  73732096)    bf16 conv out (pre-scaled), overlays dead rec
    //   Hb     : [73732096,  99946496)    bf16 gather out
    //   Bt     : [99946496,  105271296)   bf16 W1^T padded
    //   logits : [105271296, 105336832)   fp32[2*NBG]
    char* ws = (char*)d_ws;
    int*   cur  = (int*)ws;
    float* dinv = (float*)(ws + 819200);
    int*   gcur = (int*)(ws + 1638400);
    int*   csr  = (int*)(ws + 1642496);
    unsigned* rec = (unsigned*)(ws + 47517696);
    __hip_bfloat16* hbs = (__hip_bfloat16*)(ws + 47517696);
    __hip_bfloat16* Hb  = (__hip_bfloat16*)(ws + 73732096);
    __hip_bfloat16* Bt  = (__hip_bfloat16*)(ws + 99946496);
    float* logits = (float*)(ws + 105271296);

    k_init     <<<64, 256, 0, stream>>>(gcur, logits);
    k_part     <<<512, 256, 0, stream>>>(srcv, dstv, gcur, rec);
    k_fillb    <<<NBKT, 512, 0, stream>>>(gcur, rec, cur, csr, dinv);
    k_gemm_conv<<<NT / 64, 256, 0, stream>>>(x, Wc, dinv, hbs);
    k_gather   <<<NT / 4, 256, 0, stream>>>(cur, csr, dinv, hbs, bc, Hb);
    k_convW1   <<<dim3(HID / 64, HPAD / 64), 256, 0, stream>>>(W1, Bt);
    k_gemm1    <<<dim3(NBG / 128, HPAD / 128), 256, 0, stream>>>(Hb, Bt, b1, W2, logits);
    k_soft     <<<NBG / 256, 256, 0, stream>>>(logits, b2, out);
}